// Round 14
// baseline (1291.300 us; speedup 1.0000x reference)
//
#include <hip/hip_runtime.h>
#include <hip/hip_bf16.h>

typedef unsigned short ushort_t;
typedef unsigned int uint_t;
typedef unsigned char uchar_t;

typedef float f32x4 __attribute__((ext_vector_type(4)));
typedef float f32x16 __attribute__((ext_vector_type(16)));

#define NPTS (1 << 20)

// ---- ws layout (ushort units) ----
// Weights stored as fp8-e4m3 (pre-scaled x16) 32x32x16 MFMA A-fragments of
// W^T: tile = 32 out-cols (m) x 16 k; lane l: m = l&31, k = (l>>5)*8 + j
// (j = byte 0..7). Tile = 512 B = 256 ushorts. Tile order [kt][mt(8)].
#define OFF_FLAG 0        // uint flag: 1 = inputs bf16, 0 = fp32
#define OFF_B0   16
#define OFF_B1   272
#define OFF_B2   528
#define OFF_B3   784
#define OFF_BSIG 1040
#define OFF_BRGB 1041
#define OFF_W0   1056     // 4 kt x 8 mt = 32 tiles * 256
#define OFF_W1   9248     // 16 kt x 8 mt = 128 tiles * 256
#define OFF_W2   42016
#define OFF_W3   74784
#define OFF_WH   107552   // head: 16 kt x 1 mt
#define OFF_PL   111648   // transposed planes (bf16) [plane][pos(16384)][rank(8)]

__device__ __forceinline__ float bf2f(ushort_t u) {
  union { uint_t i; float f; } c; c.i = ((uint_t)u) << 16; return c.f;
}
__device__ __forceinline__ ushort_t f2bf(float f) {
  union { float f; uint_t i; } c; c.f = f;
  uint_t x = c.i;
  return (ushort_t)((x + 0x7fffu + ((x >> 16) & 1u)) >> 16);
}
// f32 -> OCP e4m3fn byte, round-to-nearest-even-ish (rintf)
__device__ __forceinline__ uint_t f2fp8b(float x) {
  union { float f; uint_t u; } v; v.f = x;
  uint_t s = (v.u >> 24) & 0x80u;
  float ax = fabsf(x);
  if (ax < 0.015625f) return s | (uint_t)(int)rintf(ax * 512.0f);  // subnormal
  if (ax >= 448.0f) return s | 0x7Eu;
  int e2; float m = frexpf(ax, &e2);          // ax = m*2^e2, m in [0.5,1)
  int q = (int)rintf(m * 16.0f) - 8;          // 0..8
  int e = e2 - 1;
  if (q == 8) { q = 0; ++e; }
  if (e == 8 && q > 6) q = 6;                 // clamp to 448
  return s | ((uint_t)(e + 7) << 3) | (uint_t)q;
}
// dtype-branched scalar loads
__device__ __forceinline__ float ldf(const void* p, long i, int isbf) {
  return isbf ? bf2f(((const ushort_t*)p)[i]) : ((const float*)p)[i];
}
__device__ __forceinline__ ushort_t ldbf(const void* p, long i, int isbf) {
  return isbf ? ((const ushort_t*)p)[i] : f2bf(((const float*)p)[i]);
}
__device__ __forceinline__ void stf(void* p, long i, int isbf, float v) {
  if (isbf) ((ushort_t*)p)[i] = f2bf(v);
  else      ((float*)p)[i] = v;
}

// Activation LDS = fp8 B-fragment native (128 pts = 4 n-tiles), BYTE address:
// (point p, col k) -> ntile(p>>5)*8192 + (k>>4)*512 + ((k>>3)&1)*256
//                     + (p&31)*8 + (k&7)
__device__ __forceinline__ int fp8addr(int p, int k) {
  return ((p >> 5) << 13) + ((k >> 4) << 9) + (((k >> 3) & 1) << 8)
       + ((p & 31) << 3) + (k & 7);
}

union UA { uint2 u; long l; };

// ------------------------------------------------------------------
__global__ void sniff_dtype(const void* __restrict__ f, ushort_t* __restrict__ ws) {
  __shared__ int s_cnt;
  if (threadIdx.x == 0) s_cnt = 0;
  __syncthreads();
  const ushort_t* u = (const ushort_t*)f;
  int c = 0;
  for (int j = 0; j < 4; ++j) {
    ushort_t v = u[(threadIdx.x * 4 + j) * 2];
    int e = (v >> 7) & 0xFF;
    if (e > 100 && e < 140) ++c;
  }
  atomicAdd(&s_cnt, c);
  __syncthreads();
  if (threadIdx.x == 0) ((uint_t*)ws)[0] = (s_cnt >= 160) ? 1u : 0u;
}

__global__ void prep_bias(const void* __restrict__ b0, const void* __restrict__ b1,
                          const void* __restrict__ b2, const void* __restrict__ b3,
                          const void* __restrict__ bsig, const void* __restrict__ brgb,
                          ushort_t* __restrict__ ws) {
  const int isbf = (int)((const uint_t*)ws)[0];
  int i = threadIdx.x;
  ws[OFF_B0 + i] = ldbf(b0, i, isbf);
  ws[OFF_B1 + i] = ldbf(b1, i, isbf);
  ws[OFF_B2 + i] = ldbf(b2, i, isbf);
  ws[OFF_B3 + i] = ldbf(b3, i, isbf);
  if (i == 0) ws[OFF_BSIG] = ldbf(bsig, 0, isbf);
  if (i < 3) ws[OFF_BRGB + i] = ldbf(brgb, i, isbf);
}

// weights -> fp8 e4m3 (x16) 32x32x16 A-frags of W^T, tile order [kt][mt]
__global__ void prep_weights(const void* __restrict__ W0,
                             const void* __restrict__ W1,
                             const void* __restrict__ W2,
                             const void* __restrict__ W3,
                             const void* __restrict__ Wsig,
                             const void* __restrict__ Wrgb,
                             ushort_t* __restrict__ ws) {
  const int isbf = (int)((const uint_t*)ws)[0];
  int t = blockIdx.x * 256 + threadIdx.x;   // 432 tiles * 64 lanes = 27648
  if (t >= 432 * 64) return;
  int lane = t & 63;
  int tile = t >> 6;
  const void* src = nullptr;
  ushort_t* dst;
  int local, Ksrc = 256;
  bool head = false;
  if (tile < 32) { local = tile; src = W0; Ksrc = 47; dst = ws + OFF_W0 + (size_t)local * 256; }
  else if (tile < 160) { local = tile - 32;  src = W1; dst = ws + OFF_W1 + (size_t)local * 256; }
  else if (tile < 288) { local = tile - 160; src = W2; dst = ws + OFF_W2 + (size_t)local * 256; }
  else if (tile < 416) { local = tile - 288; src = W3; dst = ws + OFF_W3 + (size_t)local * 256; }
  else { local = tile - 416; head = true; dst = ws + OFF_WH + (size_t)local * 256; }
  int kt = head ? local : (local >> 3);
  int mt = head ? 0 : (local & 7);
  int n = mt * 32 + (lane & 31);         // out-col (A-frag m)
  int kb = kt * 16 + (lane >> 5) * 8;    // k base
  for (int j = 0; j < 8; j += 2) {
    uint_t q[2];
    for (int jj = 0; jj < 2; ++jj) {
      int k = kb + j + jj;
      float v = 0.0f;
      if (head) {
        if (n < 3) v = ldf(Wrgb, (long)k * 3 + n, isbf);
        else if (n == 3) v = ldf(Wsig, k, isbf);
      } else if (k < Ksrc) {
        v = ldf(src, (long)k * 256 + n, isbf);
      }
      q[jj] = f2fp8b(v * 16.0f);         // x16: e4m3 normal range
    }
    dst[lane * 4 + (j >> 1)] = (ushort_t)(q[0] | (q[1] << 8));
  }
}

__global__ void prep_planes(const void* __restrict__ fxy,
                            const void* __restrict__ fxz,
                            const void* __restrict__ fyz,
                            ushort_t* __restrict__ ws) {
  const int isbf = (int)((const uint_t*)ws)[0];
  int t = blockIdx.x * 256 + threadIdx.x;   // 3*16384 = 49152
  int plane = t >> 14, pos = t & 16383;
  const void* src = (plane == 0) ? fxy : (plane == 1) ? fxz : fyz;
  ushort_t* d = ws + OFF_PL + (size_t)plane * 131072 + (size_t)pos * 8;
  for (int r = 0; r < 8; ++r) d[r] = ldbf(src, (long)r * 16384 + pos, isbf);
}

// ------------------------------------------------------------------
// main: R11 structure (453 us best, MfmaUtil 49%) ported to fp8:
// block = 256 thr / 4 waves / 128 pts, 2 waves/SIMD (256 regs).
// Wave w: out-cols [w*64, w*64+64) x all 128 pts; acc[2][4] f32x16 =
// 128 AGPRs; fp8 operands are uint2 (8 B/lane). LDS B-reads b64 (half
// of bf16), A L2 stream halves, LDS/block 32 KB. Same lane->(m,k) map
// as the verified bf16 32x32x16 kernel. A-prefetch distance 3-4 via
// 4-slot rotation; peeled last group prefetches NEXT layer tiles 0..3.
// ------------------------------------------------------------------
template <int KT>
__device__ __forceinline__ void mlp_layer(uchar_t* s_act,
                                          const uchar_t* __restrict__ wsW,
                                          const uchar_t* __restrict__ nextW,
                                          const ushort_t* __restrict__ bias,
                                          int w, int lane, UA (&a)[4][2]) {
  f32x16 acc[2][4] = {};
  const int p31 = lane & 31;
  const int q2 = lane >> 5;
  const uchar_t* bptr = s_act + lane * 8;              // + d*8192 + kt*512
  const uchar_t* aptr = wsW + w * 1024 + lane * 8;     // + kt*4096 + mi*512
  const uchar_t* nptr = nextW + w * 1024 + lane * 8;
  UA b[2][4];
#pragma unroll
  for (int d = 0; d < 4; ++d) b[0][d].u = *(const uint2*)(bptr + d * 8192);
#pragma unroll 1
  for (int g = 0; g < KT / 4 - 1; ++g) {
    const uchar_t* ag = aptr + g * 16384;
    const uchar_t* bg = bptr + g * 2048;
#pragma unroll
    for (int j = 0; j < 4; ++j) {
#pragma unroll
      for (int d = 0; d < 4; ++d)
        b[(j + 1) & 1][d].u = *(const uint2*)(bg + (j + 1) * 512 + d * 8192);
#pragma unroll
      for (int mi = 0; mi < 2; ++mi)
#pragma unroll
        for (int d = 0; d < 4; ++d)
          acc[mi][d] = __builtin_amdgcn_mfma_f32_32x32x16_fp8_fp8(a[j][mi].l, b[j & 1][d].l, acc[mi][d], 0, 0, 0);
#pragma unroll
      for (int mi = 0; mi < 2; ++mi)
        a[j][mi].u = *(const uint2*)(ag + 16384 + j * 4096 + mi * 512);
    }
  }
  {  // peeled last group; A reloads from next layer
    const uchar_t* bg = bptr + (KT / 4 - 1) * 2048;
#pragma unroll
    for (int j = 0; j < 4; ++j) {
      if (j < 3) {
#pragma unroll
        for (int d = 0; d < 4; ++d)
          b[(j + 1) & 1][d].u = *(const uint2*)(bg + (j + 1) * 512 + d * 8192);
      }
#pragma unroll
      for (int mi = 0; mi < 2; ++mi)
#pragma unroll
        for (int d = 0; d < 4; ++d)
          acc[mi][d] = __builtin_amdgcn_mfma_f32_32x32x16_fp8_fp8(a[j][mi].l, b[j & 1][d].l, acc[mi][d], 0, 0, 0);
#pragma unroll
      for (int mi = 0; mi < 2; ++mi)
        a[j][mi].u = *(const uint2*)(nptr + j * 4096 + mi * 512);
    }
  }
  __syncthreads();   // all waves done reading act
  // Epilogue: z = acc/16 + bias, relu, fp8-pack 4 cols -> one b32 write.
  uchar_t* wbase = s_act + w * 2048 + p31 * 8 + q2 * 4;
#pragma unroll
  for (int mi = 0; mi < 2; ++mi) {
#pragma unroll
    for (int rq = 0; rq < 4; ++rq) {
      int col0 = w * 64 + mi * 32 + rq * 8 + q2 * 4;
      ushort4 bb = *(const ushort4*)(bias + col0);
      float bf0 = bf2f(bb.x), bf1 = bf2f(bb.y), bf2v = bf2f(bb.z), bf3 = bf2f(bb.w);
#pragma unroll
      for (int d = 0; d < 4; ++d) {
        const f32x16& A = acc[mi][d];
        float v0 = fmaxf(A[rq * 4 + 0] * 0.0625f + bf0, 0.0f);
        float v1 = fmaxf(A[rq * 4 + 1] * 0.0625f + bf1, 0.0f);
        float v2 = fmaxf(A[rq * 4 + 2] * 0.0625f + bf2v, 0.0f);
        float v3 = fmaxf(A[rq * 4 + 3] * 0.0625f + bf3, 0.0f);
        uint_t pk = f2fp8b(v0) | (f2fp8b(v1) << 8) | (f2fp8b(v2) << 16) | (f2fp8b(v3) << 24);
        *(uint_t*)(wbase + d * 8192 + mi * 1024 + (rq >> 1) * 512 + (rq & 1) * 256) = pk;
      }
    }
  }
  __syncthreads();   // act ready for next layer
}

__global__ __launch_bounds__(256, 2)
void tensorf_main(const void* __restrict__ x,
                  const ushort_t* __restrict__ ws,
                  void* __restrict__ out) {
  __shared__ uchar_t s_act[4 * 16 * 512];   // 32 KB fp8 frag-native act
  const int isbf = (int)((const uint_t*)ws)[0];
  const int tid = threadIdx.x;
  const int lane = tid & 63;
  const int wid = tid >> 6;        // 0..3
  const int blk = blockIdx.x;

  // Layer-0 A-prefetch (tiles 0..3) first: latency hides under Phase A.
  UA a[4][2];
  {
    const uchar_t* a0 = (const uchar_t*)(ws + OFF_W0) + wid * 1024 + lane * 8;
#pragma unroll
    for (int t = 0; t < 4; ++t)
#pragma unroll
      for (int mi = 0; mi < 2; ++mi)
        a[t][mi].u = *(const uint2*)(a0 + t * 4096 + mi * 512);
  }

  // ---- Phase A: features + PE into fp8 frag layout, cols 0..63 ----
  // 2 threads per point: s=0 gather + x + lvl 4,5 + pad; s=1 lvl 0..3
  {
    int pl = tid >> 1;            // 0..127
    int s = tid & 1;
    long p = (long)blk * 128 + pl;
    float x0 = ldf(x, p * 3 + 0, isbf);
    float x1 = ldf(x, p * 3 + 1, isbf);
    float x2 = ldf(x, p * 3 + 2, isbf);
    float fx[3] = { x0, x1, x2 };
    if (s == 0) {
      int ix = (int)(((x0 + 1.0f) * 0.5f) * 127.0f);
      int iy = (int)(((x1 + 1.0f) * 0.5f) * 127.0f);
      int iz = (int)(((x2 + 1.0f) * 0.5f) * 127.0f);
      ix = ix < 0 ? 0 : (ix > 127 ? 127 : ix);
      iy = iy < 0 ? 0 : (iy > 127 ? 127 : iy);
      iz = iz < 0 ? 0 : (iz > 127 ? 127 : iz);
      union { uint4 u; ushort_t s[8]; } a4, b4, c4;
      a4.u = *(const uint4*)(ws + OFF_PL + (size_t)(iy * 128 + ix) * 8);
      b4.u = *(const uint4*)(ws + OFF_PL + 131072 + (size_t)(iz * 128 + ix) * 8);
      c4.u = *(const uint4*)(ws + OFF_PL + 262144 + (size_t)(iz * 128 + iy) * 8);
      union { uint2 u; uchar_t b[8]; } f;
#pragma unroll
      for (int r = 0; r < 8; ++r) {
        float fv = bf2f(a4.s[r]) + bf2f(b4.s[r]) + bf2f(c4.s[r]);
        f.b[r] = (uchar_t)f2fp8b(fv);
      }
      *(uint2*)(s_act + fp8addr(pl, 0)) = f.u;       // cols 0..7, 8B aligned
      s_act[fp8addr(pl, 8)]  = (uchar_t)f2fp8b(x0);
      s_act[fp8addr(pl, 9)]  = (uchar_t)f2fp8b(x1);
      s_act[fp8addr(pl, 10)] = (uchar_t)f2fp8b(x2);
#pragma unroll
      for (int l = 4; l < 6; ++l) {
        float fr = (float)(1 << l);
        int k0 = 11 + l * 6;
#pragma unroll
        for (int dd = 0; dd < 3; ++dd) {
          float ang = fx[dd] * fr;
          s_act[fp8addr(pl, k0 + dd)]     = (uchar_t)f2fp8b(__sinf(ang));
          s_act[fp8addr(pl, k0 + 3 + dd)] = (uchar_t)f2fp8b(__cosf(ang));
        }
      }
      s_act[fp8addr(pl, 47)] = 0;
      *(uint2*)(s_act + fp8addr(pl, 48)) = uint2{0u, 0u};
      *(uint2*)(s_act + fp8addr(pl, 56)) = uint2{0u, 0u};
    } else {
#pragma unroll
      for (int l = 0; l < 4; ++l) {
        float fr = (float)(1 << l);
        int k0 = 11 + l * 6;
#pragma unroll
        for (int dd = 0; dd < 3; ++dd) {
          float ang = fx[dd] * fr;
          s_act[fp8addr(pl, k0 + dd)]     = (uchar_t)f2fp8b(__sinf(ang));
          s_act[fp8addr(pl, k0 + 3 + dd)] = (uchar_t)f2fp8b(__cosf(ang));
        }
      }
    }
  }
  __syncthreads();

  const uchar_t* w0 = (const uchar_t*)(ws + OFF_W0);
  const uchar_t* w1 = (const uchar_t*)(ws + OFF_W1);
  const uchar_t* w2 = (const uchar_t*)(ws + OFF_W2);
  const uchar_t* w3 = (const uchar_t*)(ws + OFF_W3);
  const uchar_t* wh = (const uchar_t*)(ws + OFF_WH);
  mlp_layer<4>(s_act,  w0, w1, ws + OFF_B0, wid, lane, a);
  mlp_layer<16>(s_act, w1, w2, ws + OFF_B1, wid, lane, a);
  mlp_layer<16>(s_act, w2, w3, ws + OFF_B2, wid, lane, a);
  mlp_layer<16>(s_act, w3, wh, ws + OFF_B3, wid, lane, a);

  // ---- head: D = Wh^T(32x256, cols 0..3 real) x Act^T; wave w = n-tile w ----
  {
    f32x16 acc = {};
    const int p31 = lane & 31;
    const int q2 = lane >> 5;
    const uchar_t* hb = s_act + wid * 8192 + lane * 8;
    const uchar_t* whp = wh + lane * 8;
#pragma unroll 4
    for (int kt = 0; kt < 16; ++kt) {
      UA ta, tb;
      ta.u = *(const uint2*)(whp + kt * 512);
      tb.u = *(const uint2*)(hb + kt * 512);
      acc = __builtin_amdgcn_mfma_f32_32x32x16_fp8_fp8(ta.l, tb.l, acc, 0, 0, 0);
    }
    if (q2 == 0) {   // regs 0..3 = cols 0..3 = rgb0, rgb1, rgb2, sigma
      long pp = (long)blk * 128 + wid * 32 + p31;
      float br0 = bf2f(ws[OFF_BRGB + 0]), br1 = bf2f(ws[OFF_BRGB + 1]), br2 = bf2f(ws[OFF_BRGB + 2]);
      float bs = bf2f(ws[OFF_BSIG]);
      float z0 = acc[0] * 0.0625f + br0, z1 = acc[1] * 0.0625f + br1, z2 = acc[2] * 0.0625f + br2;
      stf(out, pp * 3 + 0, isbf, 1.0f / (1.0f + __expf(-z0)));
      stf(out, pp * 3 + 1, isbf, 1.0f / (1.0f + __expf(-z1)));
      stf(out, pp * 3 + 2, isbf, 1.0f / (1.0f + __expf(-z2)));
      float zs = acc[3] * 0.0625f + bs;
      float sp = (zs > 20.0f) ? zs : __logf(1.0f + __expf(zs));
      stf(out, (long)3 * NPTS + pp, isbf, sp);
    }
  }
}

extern "C" void kernel_launch(void* const* d_in, const int* in_sizes, int n_in,
                              void* d_out, int out_size, void* d_ws, size_t ws_size,
                              hipStream_t stream) {
  const void* x    = d_in[0];
  const void* fxy  = d_in[1];
  const void* fxz  = d_in[2];
  const void* fyz  = d_in[3];
  const void* W0   = d_in[4];
  const void* b0   = d_in[5];
  const void* W1   = d_in[6];
  const void* b1   = d_in[7];
  const void* W2   = d_in[8];
  const void* b2   = d_in[9];
  const void* W3   = d_in[10];
  const void* b3   = d_in[11];
  const void* Wsig = d_in[12];
  const void* bsig = d_in[13];
  const void* Wrgb = d_in[14];
  const void* brgb = d_in[15];
  ushort_t* ws = (ushort_t*)d_ws;

  hipLaunchKernelGGL(sniff_dtype, dim3(1), dim3(64), 0, stream, fxy, ws);
  hipLaunchKernelGGL(prep_bias, dim3(1), dim3(256), 0, stream,
                     b0, b1, b2, b3, bsig, brgb, ws);
  hipLaunchKernelGGL(prep_weights, dim3(108), dim3(256), 0, stream,
                     W0, W1, W2, W3, Wsig, Wrgb, ws);
  hipLaunchKernelGGL(prep_planes, dim3(192), dim3(256), 0, stream,
                     fxy, fxz, fyz, ws);
  hipLaunchKernelGGL(tensorf_main, dim3(8192), dim3(256), 0, stream,
                     x, ws, d_out);
}

// Round 15
// 440.925 us; speedup vs baseline: 2.9286x; 2.9286x over previous
//
#include <hip/hip_runtime.h>
#include <hip/hip_bf16.h>

typedef unsigned short ushort_t;
typedef unsigned int uint_t;
typedef unsigned char uchar_t;

typedef float f32x4 __attribute__((ext_vector_type(4)));
typedef float f32x16 __attribute__((ext_vector_type(16)));

#define NPTS (1 << 20)

// ---- ws layout (ushort units) ----
// Weights stored as fp8-e4m3 (pre-scaled x16) 32x32x16 MFMA A-fragments of
// W^T: tile = 32 out-cols (m) x 16 k; lane l: m = l&31, k = (l>>5)*8 + j
// (j = byte 0..7). Tile = 512 B = 256 ushorts. Tile order [kt][mt(8)].
#define OFF_FLAG 0        // uint flag: 1 = inputs bf16, 0 = fp32
#define OFF_B0   16
#define OFF_B1   272
#define OFF_B2   528
#define OFF_B3   784
#define OFF_BSIG 1040
#define OFF_BRGB 1041
#define OFF_W0   1056     // 4 kt x 8 mt = 32 tiles * 256
#define OFF_W1   9248     // 16 kt x 8 mt = 128 tiles * 256
#define OFF_W2   42016
#define OFF_W3   74784
#define OFF_WH   107552   // head: 16 kt x 1 mt
#define OFF_PL   111648   // transposed planes (bf16) [plane][pos(16384)][rank(8)]

__device__ __forceinline__ float bf2f(ushort_t u) {
  union { uint_t i; float f; } c; c.i = ((uint_t)u) << 16; return c.f;
}
__device__ __forceinline__ ushort_t f2bf(float f) {
  union { float f; uint_t i; } c; c.f = f;
  uint_t x = c.i;
  return (ushort_t)((x + 0x7fffu + ((x >> 16) & 1u)) >> 16);
}
// soft f32 -> OCP e4m3fn (fallback only)
__device__ __forceinline__ uint_t f2fp8b_soft(float x) {
  union { float f; uint_t u; } v; v.f = x;
  uint_t s = (v.u >> 24) & 0x80u;
  float ax = fabsf(x);
  if (ax < 0.015625f) return s | (uint_t)(int)rintf(ax * 512.0f);
  if (ax >= 448.0f) return s | 0x7Eu;
  int e2; float m = frexpf(ax, &e2);
  int q = (int)rintf(m * 16.0f) - 8;
  int e = e2 - 1;
  if (q == 8) { q = 0; ++e; }
  if (e == 8 && q > 6) q = 6;
  return s | ((uint_t)(e + 7) << 3) | (uint_t)q;
}

// HW packed f32x2 -> fp8x2 (v_cvt_pk_fp8_f32; OCP e4m3fn on gfx950).
// Round-14 post-mortem: the soft converter cost ~860 us of VALU.
#if defined(__has_builtin)
#if __has_builtin(__builtin_amdgcn_cvt_pk_fp8_f32)
#define HAVE_HW_FP8 1
#endif
#endif

#ifdef HAVE_HW_FP8
__device__ __forceinline__ uint_t pk4fp8(float a, float b, float c, float d) {
  uint_t r = (uint_t)__builtin_amdgcn_cvt_pk_fp8_f32(a, b, 0, false);   // bytes 0,1
  r = (uint_t)__builtin_amdgcn_cvt_pk_fp8_f32(c, d, r, true);           // bytes 2,3
  return r;
}
__device__ __forceinline__ uchar_t f2fp8(float x) {
  return (uchar_t)(__builtin_amdgcn_cvt_pk_fp8_f32(x, 0.0f, 0, false) & 0xFFu);
}
#else
__device__ __forceinline__ uint_t pk4fp8(float a, float b, float c, float d) {
  return f2fp8b_soft(a) | (f2fp8b_soft(b) << 8) | (f2fp8b_soft(c) << 16) | (f2fp8b_soft(d) << 24);
}
__device__ __forceinline__ uchar_t f2fp8(float x) { return (uchar_t)f2fp8b_soft(x); }
#endif

// dtype-branched scalar loads
__device__ __forceinline__ float ldf(const void* p, long i, int isbf) {
  return isbf ? bf2f(((const ushort_t*)p)[i]) : ((const float*)p)[i];
}
__device__ __forceinline__ ushort_t ldbf(const void* p, long i, int isbf) {
  return isbf ? ((const ushort_t*)p)[i] : f2bf(((const float*)p)[i]);
}
__device__ __forceinline__ void stf(void* p, long i, int isbf, float v) {
  if (isbf) ((ushort_t*)p)[i] = f2bf(v);
  else      ((float*)p)[i] = v;
}

// Activation LDS = fp8 B-fragment native (128 pts = 4 n-tiles), BYTE address:
// (point p, col k) -> ntile(p>>5)*8192 + (k>>4)*512 + ((k>>3)&1)*256
//                     + (p&31)*8 + (k&7)
__device__ __forceinline__ int fp8addr(int p, int k) {
  return ((p >> 5) << 13) + ((k >> 4) << 9) + (((k >> 3) & 1) << 8)
       + ((p & 31) << 3) + (k & 7);
}

union UA { uint2 u; long l; };

// ------------------------------------------------------------------
__global__ void sniff_dtype(const void* __restrict__ f, ushort_t* __restrict__ ws) {
  __shared__ int s_cnt;
  if (threadIdx.x == 0) s_cnt = 0;
  __syncthreads();
  const ushort_t* u = (const ushort_t*)f;
  int c = 0;
  for (int j = 0; j < 4; ++j) {
    ushort_t v = u[(threadIdx.x * 4 + j) * 2];
    int e = (v >> 7) & 0xFF;
    if (e > 100 && e < 140) ++c;
  }
  atomicAdd(&s_cnt, c);
  __syncthreads();
  if (threadIdx.x == 0) ((uint_t*)ws)[0] = (s_cnt >= 160) ? 1u : 0u;
}

__global__ void prep_bias(const void* __restrict__ b0, const void* __restrict__ b1,
                          const void* __restrict__ b2, const void* __restrict__ b3,
                          const void* __restrict__ bsig, const void* __restrict__ brgb,
                          ushort_t* __restrict__ ws) {
  const int isbf = (int)((const uint_t*)ws)[0];
  int i = threadIdx.x;
  ws[OFF_B0 + i] = ldbf(b0, i, isbf);
  ws[OFF_B1 + i] = ldbf(b1, i, isbf);
  ws[OFF_B2 + i] = ldbf(b2, i, isbf);
  ws[OFF_B3 + i] = ldbf(b3, i, isbf);
  if (i == 0) ws[OFF_BSIG] = ldbf(bsig, 0, isbf);
  if (i < 3) ws[OFF_BRGB + i] = ldbf(brgb, i, isbf);
}

// weights -> fp8 e4m3 (x16) 32x32x16 A-frags of W^T, tile order [kt][mt]
__global__ void prep_weights(const void* __restrict__ W0,
                             const void* __restrict__ W1,
                             const void* __restrict__ W2,
                             const void* __restrict__ W3,
                             const void* __restrict__ Wsig,
                             const void* __restrict__ Wrgb,
                             ushort_t* __restrict__ ws) {
  const int isbf = (int)((const uint_t*)ws)[0];
  int t = blockIdx.x * 256 + threadIdx.x;   // 432 tiles * 64 lanes = 27648
  if (t >= 432 * 64) return;
  int lane = t & 63;
  int tile = t >> 6;
  const void* src = nullptr;
  ushort_t* dst;
  int local, Ksrc = 256;
  bool head = false;
  if (tile < 32) { local = tile; src = W0; Ksrc = 47; dst = ws + OFF_W0 + (size_t)local * 256; }
  else if (tile < 160) { local = tile - 32;  src = W1; dst = ws + OFF_W1 + (size_t)local * 256; }
  else if (tile < 288) { local = tile - 160; src = W2; dst = ws + OFF_W2 + (size_t)local * 256; }
  else if (tile < 416) { local = tile - 288; src = W3; dst = ws + OFF_W3 + (size_t)local * 256; }
  else { local = tile - 416; head = true; dst = ws + OFF_WH + (size_t)local * 256; }
  int kt = head ? local : (local >> 3);
  int mt = head ? 0 : (local & 7);
  int n = mt * 32 + (lane & 31);         // out-col (A-frag m)
  int kb = kt * 16 + (lane >> 5) * 8;    // k base
  for (int j = 0; j < 8; j += 4) {
    float v[4];
    for (int jj = 0; jj < 4; ++jj) {
      int k = kb + j + jj;
      float vv = 0.0f;
      if (head) {
        if (n < 3) vv = ldf(Wrgb, (long)k * 3 + n, isbf);
        else if (n == 3) vv = ldf(Wsig, k, isbf);
      } else if (k < Ksrc) {
        vv = ldf(src, (long)k * 256 + n, isbf);
      }
      v[jj] = vv * 16.0f;                // x16: e4m3 normal range
    }
    uint_t pk = pk4fp8(v[0], v[1], v[2], v[3]);
    dst[lane * 4 + (j >> 1)]     = (ushort_t)(pk & 0xFFFFu);
    dst[lane * 4 + (j >> 1) + 1] = (ushort_t)(pk >> 16);
  }
}

__global__ void prep_planes(const void* __restrict__ fxy,
                            const void* __restrict__ fxz,
                            const void* __restrict__ fyz,
                            ushort_t* __restrict__ ws) {
  const int isbf = (int)((const uint_t*)ws)[0];
  int t = blockIdx.x * 256 + threadIdx.x;   // 3*16384 = 49152
  int plane = t >> 14, pos = t & 16383;
  const void* src = (plane == 0) ? fxy : (plane == 1) ? fxz : fyz;
  ushort_t* d = ws + OFF_PL + (size_t)plane * 131072 + (size_t)pos * 8;
  for (int r = 0; r < 8; ++r) d[r] = ldbf(src, (long)r * 16384 + pos, isbf);
}

// ------------------------------------------------------------------
// main: R11 structure ported to fp8 (round 14) + HW fp8 converters
// (round 15). block = 256 thr / 4 waves / 128 pts, 2 waves/SIMD.
// Wave w: out-cols [w*64, w*64+64) x all 128 pts; acc[2][4] f32x16 =
// 128 AGPRs; fp8 operands uint2 (8 B/lane). LDS B-reads b64, A L2
// stream 1.75 GB, LDS 32 KB/block. A-prefetch distance 3-4 via 4-slot
// rotation; peeled last group prefetches NEXT layer tiles 0..3.
// ------------------------------------------------------------------
template <int KT>
__device__ __forceinline__ void mlp_layer(uchar_t* s_act,
                                          const uchar_t* __restrict__ wsW,
                                          const uchar_t* __restrict__ nextW,
                                          const ushort_t* __restrict__ bias,
                                          int w, int lane, UA (&a)[4][2]) {
  f32x16 acc[2][4] = {};
  const int p31 = lane & 31;
  const int q2 = lane >> 5;
  const uchar_t* bptr = s_act + lane * 8;              // + d*8192 + kt*512
  const uchar_t* aptr = wsW + w * 1024 + lane * 8;     // + kt*4096 + mi*512
  const uchar_t* nptr = nextW + w * 1024 + lane * 8;
  UA b[2][4];
#pragma unroll
  for (int d = 0; d < 4; ++d) b[0][d].u = *(const uint2*)(bptr + d * 8192);
#pragma unroll 1
  for (int g = 0; g < KT / 4 - 1; ++g) {
    const uchar_t* ag = aptr + g * 16384;
    const uchar_t* bg = bptr + g * 2048;
#pragma unroll
    for (int j = 0; j < 4; ++j) {
#pragma unroll
      for (int d = 0; d < 4; ++d)
        b[(j + 1) & 1][d].u = *(const uint2*)(bg + (j + 1) * 512 + d * 8192);
#pragma unroll
      for (int mi = 0; mi < 2; ++mi)
#pragma unroll
        for (int d = 0; d < 4; ++d)
          acc[mi][d] = __builtin_amdgcn_mfma_f32_32x32x16_fp8_fp8(a[j][mi].l, b[j & 1][d].l, acc[mi][d], 0, 0, 0);
#pragma unroll
      for (int mi = 0; mi < 2; ++mi)
        a[j][mi].u = *(const uint2*)(ag + 16384 + j * 4096 + mi * 512);
    }
  }
  {  // peeled last group; A reloads from next layer
    const uchar_t* bg = bptr + (KT / 4 - 1) * 2048;
#pragma unroll
    for (int j = 0; j < 4; ++j) {
      if (j < 3) {
#pragma unroll
        for (int d = 0; d < 4; ++d)
          b[(j + 1) & 1][d].u = *(const uint2*)(bg + (j + 1) * 512 + d * 8192);
      }
#pragma unroll
      for (int mi = 0; mi < 2; ++mi)
#pragma unroll
        for (int d = 0; d < 4; ++d)
          acc[mi][d] = __builtin_amdgcn_mfma_f32_32x32x16_fp8_fp8(a[j][mi].l, b[j & 1][d].l, acc[mi][d], 0, 0, 0);
#pragma unroll
      for (int mi = 0; mi < 2; ++mi)
        a[j][mi].u = *(const uint2*)(nptr + j * 4096 + mi * 512);
    }
  }
  __syncthreads();   // all waves done reading act
  // Epilogue: z = acc/16 + bias (fmaf), relu, HW fp8-pack 4 cols -> b32 write.
  uchar_t* wbase = s_act + w * 2048 + p31 * 8 + q2 * 4;
#pragma unroll
  for (int mi = 0; mi < 2; ++mi) {
#pragma unroll
    for (int rq = 0; rq < 4; ++rq) {
      int col0 = w * 64 + mi * 32 + rq * 8 + q2 * 4;
      ushort4 bb = *(const ushort4*)(bias + col0);
      float bf0 = bf2f(bb.x), bf1 = bf2f(bb.y), bf2v = bf2f(bb.z), bf3 = bf2f(bb.w);
#pragma unroll
      for (int d = 0; d < 4; ++d) {
        const f32x16& A = acc[mi][d];
        float v0 = fmaxf(fmaf(A[rq * 4 + 0], 0.0625f, bf0), 0.0f);
        float v1 = fmaxf(fmaf(A[rq * 4 + 1], 0.0625f, bf1), 0.0f);
        float v2 = fmaxf(fmaf(A[rq * 4 + 2], 0.0625f, bf2v), 0.0f);
        float v3 = fmaxf(fmaf(A[rq * 4 + 3], 0.0625f, bf3), 0.0f);
        *(uint_t*)(wbase + d * 8192 + mi * 1024 + (rq >> 1) * 512 + (rq & 1) * 256)
            = pk4fp8(v0, v1, v2, v3);
      }
    }
  }
  __syncthreads();   // act ready for next layer
}

__global__ __launch_bounds__(256, 2)
void tensorf_main(const void* __restrict__ x,
                  const ushort_t* __restrict__ ws,
                  void* __restrict__ out) {
  __shared__ uchar_t s_act[4 * 16 * 512];   // 32 KB fp8 frag-native act
  const int isbf = (int)((const uint_t*)ws)[0];
  const int tid = threadIdx.x;
  const int lane = tid & 63;
  const int wid = tid >> 6;        // 0..3
  const int blk = blockIdx.x;

  // Layer-0 A-prefetch (tiles 0..3) first: latency hides under Phase A.
  UA a[4][2];
  {
    const uchar_t* a0 = (const uchar_t*)(ws + OFF_W0) + wid * 1024 + lane * 8;
#pragma unroll
    for (int t = 0; t < 4; ++t)
#pragma unroll
      for (int mi = 0; mi < 2; ++mi)
        a[t][mi].u = *(const uint2*)(a0 + t * 4096 + mi * 512);
  }

  // ---- Phase A: features + PE into fp8 frag layout, cols 0..63 ----
  // 2 threads per point: s=0 gather + x + lvl 4,5 + pad; s=1 lvl 0..3
  {
    int pl = tid >> 1;            // 0..127
    int s = tid & 1;
    long p = (long)blk * 128 + pl;
    float x0 = ldf(x, p * 3 + 0, isbf);
    float x1 = ldf(x, p * 3 + 1, isbf);
    float x2 = ldf(x, p * 3 + 2, isbf);
    float fx[3] = { x0, x1, x2 };
    if (s == 0) {
      int ix = (int)(((x0 + 1.0f) * 0.5f) * 127.0f);
      int iy = (int)(((x1 + 1.0f) * 0.5f) * 127.0f);
      int iz = (int)(((x2 + 1.0f) * 0.5f) * 127.0f);
      ix = ix < 0 ? 0 : (ix > 127 ? 127 : ix);
      iy = iy < 0 ? 0 : (iy > 127 ? 127 : iy);
      iz = iz < 0 ? 0 : (iz > 127 ? 127 : iz);
      union { uint4 u; ushort_t s[8]; } a4, b4, c4;
      a4.u = *(const uint4*)(ws + OFF_PL + (size_t)(iy * 128 + ix) * 8);
      b4.u = *(const uint4*)(ws + OFF_PL + 131072 + (size_t)(iz * 128 + ix) * 8);
      c4.u = *(const uint4*)(ws + OFF_PL + 262144 + (size_t)(iz * 128 + iy) * 8);
      float fv[8];
#pragma unroll
      for (int r = 0; r < 8; ++r)
        fv[r] = bf2f(a4.s[r]) + bf2f(b4.s[r]) + bf2f(c4.s[r]);
      uint2 f;
      f.x = pk4fp8(fv[0], fv[1], fv[2], fv[3]);
      f.y = pk4fp8(fv[4], fv[5], fv[6], fv[7]);
      *(uint2*)(s_act + fp8addr(pl, 0)) = f;         // cols 0..7, 8B aligned
      s_act[fp8addr(pl, 8)]  = f2fp8(x0);
      s_act[fp8addr(pl, 9)]  = f2fp8(x1);
      s_act[fp8addr(pl, 10)] = f2fp8(x2);
#pragma unroll
      for (int l = 4; l < 6; ++l) {
        float fr = (float)(1 << l);
        int k0 = 11 + l * 6;
#pragma unroll
        for (int dd = 0; dd < 3; ++dd) {
          float ang = fx[dd] * fr;
          s_act[fp8addr(pl, k0 + dd)]     = f2fp8(__sinf(ang));
          s_act[fp8addr(pl, k0 + 3 + dd)] = f2fp8(__cosf(ang));
        }
      }
      s_act[fp8addr(pl, 47)] = 0;
      *(uint2*)(s_act + fp8addr(pl, 48)) = uint2{0u, 0u};
      *(uint2*)(s_act + fp8addr(pl, 56)) = uint2{0u, 0u};
    } else {
#pragma unroll
      for (int l = 0; l < 4; ++l) {
        float fr = (float)(1 << l);
        int k0 = 11 + l * 6;
#pragma unroll
        for (int dd = 0; dd < 3; ++dd) {
          float ang = fx[dd] * fr;
          s_act[fp8addr(pl, k0 + dd)]     = f2fp8(__sinf(ang));
          s_act[fp8addr(pl, k0 + 3 + dd)] = f2fp8(__cosf(ang));
        }
      }
    }
  }
  __syncthreads();

  const uchar_t* w0 = (const uchar_t*)(ws + OFF_W0);
  const uchar_t* w1 = (const uchar_t*)(ws + OFF_W1);
  const uchar_t* w2 = (const uchar_t*)(ws + OFF_W2);
  const uchar_t* w3 = (const uchar_t*)(ws + OFF_W3);
  const uchar_t* wh = (const uchar_t*)(ws + OFF_WH);
  mlp_layer<4>(s_act,  w0, w1, ws + OFF_B0, wid, lane, a);
  mlp_layer<16>(s_act, w1, w2, ws + OFF_B1, wid, lane, a);
  mlp_layer<16>(s_act, w2, w3, ws + OFF_B2, wid, lane, a);
  mlp_layer<16>(s_act, w3, wh, ws + OFF_B3, wid, lane, a);

  // ---- head: D = Wh^T(32x256, cols 0..3 real) x Act^T; wave w = n-tile w ----
  {
    f32x16 acc = {};
    const int p31 = lane & 31;
    const int q2 = lane >> 5;
    const uchar_t* hb = s_act + wid * 8192 + lane * 8;
    const uchar_t* whp = wh + lane * 8;
#pragma unroll 4
    for (int kt = 0; kt < 16; ++kt) {
      UA ta, tb;
      ta.u = *(const uint2*)(whp + kt * 512);
      tb.u = *(const uint2*)(hb + kt * 512);
      acc = __builtin_amdgcn_mfma_f32_32x32x16_fp8_fp8(ta.l, tb.l, acc, 0, 0, 0);
    }
    if (q2 == 0) {   // regs 0..3 = cols 0..3 = rgb0, rgb1, rgb2, sigma
      long pp = (long)blk * 128 + wid * 32 + p31;
      float br0 = bf2f(ws[OFF_BRGB + 0]), br1 = bf2f(ws[OFF_BRGB + 1]), br2 = bf2f(ws[OFF_BRGB + 2]);
      float bs = bf2f(ws[OFF_BSIG]);
      float z0 = fmaf(acc[0], 0.0625f, br0);
      float z1 = fmaf(acc[1], 0.0625f, br1);
      float z2 = fmaf(acc[2], 0.0625f, br2);
      stf(out, pp * 3 + 0, isbf, 1.0f / (1.0f + __expf(-z0)));
      stf(out, pp * 3 + 1, isbf, 1.0f / (1.0f + __expf(-z1)));
      stf(out, pp * 3 + 2, isbf, 1.0f / (1.0f + __expf(-z2)));
      float zs = fmaf(acc[3], 0.0625f, bs);
      float sp = (zs > 20.0f) ? zs : __logf(1.0f + __expf(zs));
      stf(out, (long)3 * NPTS + pp, isbf, sp);
    }
  }
}

extern "C" void kernel_launch(void* const* d_in, const int* in_sizes, int n_in,
                              void* d_out, int out_size, void* d_ws, size_t ws_size,
                              hipStream_t stream) {
  const void* x    = d_in[0];
  const void* fxy  = d_in[1];
  const void* fxz  = d_in[2];
  const void* fyz  = d_in[3];
  const void* W0   = d_in[4];
  const void* b0   = d_in[5];
  const void* W1   = d_in[6];
  const void* b1   = d_in[7];
  const void* W2   = d_in[8];
  const void* b2   = d_in[9];
  const void* W3   = d_in[10];
  const void* b3   = d_in[11];
  const void* Wsig = d_in[12];
  const void* bsig = d_in[13];
  const void* Wrgb = d_in[14];
  const void* brgb = d_in[15];
  ushort_t* ws = (ushort_t*)d_ws;

  hipLaunchKernelGGL(sniff_dtype, dim3(1), dim3(64), 0, stream, fxy, ws);
  hipLaunchKernelGGL(prep_bias, dim3(1), dim3(256), 0, stream,
                     b0, b1, b2, b3, bsig, brgb, ws);
  hipLaunchKernelGGL(prep_weights, dim3(108), dim3(256), 0, stream,
                     W0, W1, W2, W3, Wsig, Wrgb, ws);
  hipLaunchKernelGGL(prep_planes, dim3(192), dim3(256), 0, stream,
                     fxy, fxz, fyz, ws);
  hipLaunchKernelGGL(tensorf_main, dim3(8192), dim3(256), 0, stream,
                     x, ws, d_out);
}

// Round 16
// 355.065 us; speedup vs baseline: 3.6368x; 1.2418x over previous
//
#include <hip/hip_runtime.h>
#include <hip/hip_bf16.h>

typedef unsigned short ushort_t;
typedef unsigned int uint_t;
typedef unsigned char uchar_t;

typedef float f32x4 __attribute__((ext_vector_type(4)));
typedef float f32x16 __attribute__((ext_vector_type(16)));
typedef int v8i __attribute__((ext_vector_type(8)));

#define NPTS (1 << 20)

// ---- ws layout (ushort units) ----
// Weights stored as fp8-e4m3 (pre-scaled x16) 32x32x16 MFMA A-fragments of
// W^T: tile = 32 out-cols (m) x 16 k; lane l: m = l&31, k = (l>>5)*8 + j
// (j = byte 0..7). Tile = 512 B = 256 ushorts. Tile order [kt][mt(8)].
// An MX K=64 operand = 4 consecutive kt tiles packed into 8 VGPRs.
#define OFF_FLAG 0        // uint flag: 1 = inputs bf16, 0 = fp32
#define OFF_B0   16
#define OFF_B1   272
#define OFF_B2   528
#define OFF_B3   784
#define OFF_BSIG 1040
#define OFF_BRGB 1041
#define OFF_W0   1056     // 4 kt x 8 mt = 32 tiles * 256
#define OFF_W1   9248     // 16 kt x 8 mt = 128 tiles * 256
#define OFF_W2   42016
#define OFF_W3   74784
#define OFF_WH   107552   // head: 16 kt x 1 mt
#define OFF_PL   111648   // transposed planes (bf16) [plane][pos(16384)][rank(8)]

__device__ __forceinline__ float bf2f(ushort_t u) {
  union { uint_t i; float f; } c; c.i = ((uint_t)u) << 16; return c.f;
}
__device__ __forceinline__ ushort_t f2bf(float f) {
  union { float f; uint_t i; } c; c.f = f;
  uint_t x = c.i;
  return (ushort_t)((x + 0x7fffu + ((x >> 16) & 1u)) >> 16);
}
// soft f32 -> OCP e4m3fn (fallback only)
__device__ __forceinline__ uint_t f2fp8b_soft(float x) {
  union { float f; uint_t u; } v; v.f = x;
  uint_t s = (v.u >> 24) & 0x80u;
  float ax = fabsf(x);
  if (ax < 0.015625f) return s | (uint_t)(int)rintf(ax * 512.0f);
  if (ax >= 448.0f) return s | 0x7Eu;
  int e2; float m = frexpf(ax, &e2);
  int q = (int)rintf(m * 16.0f) - 8;
  int e = e2 - 1;
  if (q == 8) { q = 0; ++e; }
  if (e == 8 && q > 6) q = 6;
  return s | ((uint_t)(e + 7) << 3) | (uint_t)q;
}

#if defined(__has_builtin)
#if __has_builtin(__builtin_amdgcn_cvt_pk_fp8_f32)
#define HAVE_HW_FP8 1
#endif
#if __has_builtin(__builtin_amdgcn_mfma_scale_f32_32x32x64_f8f6f4)
#define HAVE_MX 1
#endif
#endif

#ifdef HAVE_HW_FP8
__device__ __forceinline__ uint_t pk4fp8(float a, float b, float c, float d) {
  uint_t r = (uint_t)__builtin_amdgcn_cvt_pk_fp8_f32(a, b, 0, false);   // bytes 0,1
  r = (uint_t)__builtin_amdgcn_cvt_pk_fp8_f32(c, d, r, true);           // bytes 2,3
  return r;
}
__device__ __forceinline__ uchar_t f2fp8(float x) {
  return (uchar_t)(__builtin_amdgcn_cvt_pk_fp8_f32(x, 0.0f, 0, false) & 0xFFu);
}
#else
__device__ __forceinline__ uint_t pk4fp8(float a, float b, float c, float d) {
  return f2fp8b_soft(a) | (f2fp8b_soft(b) << 8) | (f2fp8b_soft(c) << 16) | (f2fp8b_soft(d) << 24);
}
__device__ __forceinline__ uchar_t f2fp8(float x) { return (uchar_t)f2fp8b_soft(x); }
#endif

// MX operand: 4 K=16 fragment tiles (8B each) packed into 8 VGPRs.
union AU { v8i v; uint2 u2[4]; long l[4]; };

// One MX K=64 step (unit E8M0 scales = 0x7F -> 2^0). Fallback: 4 chained
// x16 fp8 MFMAs — mathematically identical; also the layout oracle: any
// within-lane k-permutation cancels between A and B (same storage map).
__device__ __forceinline__ f32x16 mx_mfma(const AU& A, const AU& B, f32x16 C) {
#ifdef HAVE_MX
  return __builtin_amdgcn_mfma_scale_f32_32x32x64_f8f6f4(
      A.v, B.v, C, 0, 0, 0, (int)0x7F7F7F7F, 0, (int)0x7F7F7F7F);
#else
#pragma unroll
  for (int s = 0; s < 4; ++s)
    C = __builtin_amdgcn_mfma_f32_32x32x16_fp8_fp8(A.l[s], B.l[s], C, 0, 0, 0);
  return C;
#endif
}

// dtype-branched scalar loads
__device__ __forceinline__ float ldf(const void* p, long i, int isbf) {
  return isbf ? bf2f(((const ushort_t*)p)[i]) : ((const float*)p)[i];
}
__device__ __forceinline__ ushort_t ldbf(const void* p, long i, int isbf) {
  return isbf ? ((const ushort_t*)p)[i] : f2bf(((const float*)p)[i]);
}
__device__ __forceinline__ void stf(void* p, long i, int isbf, float v) {
  if (isbf) ((ushort_t*)p)[i] = f2bf(v);
  else      ((float*)p)[i] = v;
}

// Activation LDS = fp8 B-fragment native (128 pts = 4 n-tiles), BYTE address:
// (point p, col k) -> ntile(p>>5)*8192 + (k>>4)*512 + ((k>>3)&1)*256
//                     + (p&31)*8 + (k&7)
__device__ __forceinline__ int fp8addr(int p, int k) {
  return ((p >> 5) << 13) + ((k >> 4) << 9) + (((k >> 3) & 1) << 8)
       + ((p & 31) << 3) + (k & 7);
}

// ------------------------------------------------------------------
__global__ void sniff_dtype(const void* __restrict__ f, ushort_t* __restrict__ ws) {
  __shared__ int s_cnt;
  if (threadIdx.x == 0) s_cnt = 0;
  __syncthreads();
  const ushort_t* u = (const ushort_t*)f;
  int c = 0;
  for (int j = 0; j < 4; ++j) {
    ushort_t v = u[(threadIdx.x * 4 + j) * 2];
    int e = (v >> 7) & 0xFF;
    if (e > 100 && e < 140) ++c;
  }
  atomicAdd(&s_cnt, c);
  __syncthreads();
  if (threadIdx.x == 0) ((uint_t*)ws)[0] = (s_cnt >= 160) ? 1u : 0u;
}

__global__ void prep_bias(const void* __restrict__ b0, const void* __restrict__ b1,
                          const void* __restrict__ b2, const void* __restrict__ b3,
                          const void* __restrict__ bsig, const void* __restrict__ brgb,
                          ushort_t* __restrict__ ws) {
  const int isbf = (int)((const uint_t*)ws)[0];
  int i = threadIdx.x;
  ws[OFF_B0 + i] = ldbf(b0, i, isbf);
  ws[OFF_B1 + i] = ldbf(b1, i, isbf);
  ws[OFF_B2 + i] = ldbf(b2, i, isbf);
  ws[OFF_B3 + i] = ldbf(b3, i, isbf);
  if (i == 0) ws[OFF_BSIG] = ldbf(bsig, 0, isbf);
  if (i < 3) ws[OFF_BRGB + i] = ldbf(brgb, i, isbf);
}

// weights -> fp8 e4m3 (x16) 32x32x16 A-frags of W^T, tile order [kt][mt]
__global__ void prep_weights(const void* __restrict__ W0,
                             const void* __restrict__ W1,
                             const void* __restrict__ W2,
                             const void* __restrict__ W3,
                             const void* __restrict__ Wsig,
                             const void* __restrict__ Wrgb,
                             ushort_t* __restrict__ ws) {
  const int isbf = (int)((const uint_t*)ws)[0];
  int t = blockIdx.x * 256 + threadIdx.x;   // 432 tiles * 64 lanes = 27648
  if (t >= 432 * 64) return;
  int lane = t & 63;
  int tile = t >> 6;
  const void* src = nullptr;
  ushort_t* dst;
  int local, Ksrc = 256;
  bool head = false;
  if (tile < 32) { local = tile; src = W0; Ksrc = 47; dst = ws + OFF_W0 + (size_t)local * 256; }
  else if (tile < 160) { local = tile - 32;  src = W1; dst = ws + OFF_W1 + (size_t)local * 256; }
  else if (tile < 288) { local = tile - 160; src = W2; dst = ws + OFF_W2 + (size_t)local * 256; }
  else if (tile < 416) { local = tile - 288; src = W3; dst = ws + OFF_W3 + (size_t)local * 256; }
  else { local = tile - 416; head = true; dst = ws + OFF_WH + (size_t)local * 256; }
  int kt = head ? local : (local >> 3);
  int mt = head ? 0 : (local & 7);
  int n = mt * 32 + (lane & 31);         // out-col (A-frag m)
  int kb = kt * 16 + (lane >> 5) * 8;    // k base
  for (int j = 0; j < 8; j += 4) {
    float v[4];
    for (int jj = 0; jj < 4; ++jj) {
      int k = kb + j + jj;
      float vv = 0.0f;
      if (head) {
        if (n < 3) vv = ldf(Wrgb, (long)k * 3 + n, isbf);
        else if (n == 3) vv = ldf(Wsig, k, isbf);
      } else if (k < Ksrc) {
        vv = ldf(src, (long)k * 256 + n, isbf);
      }
      v[jj] = vv * 16.0f;                // x16: e4m3 normal range
    }
    uint_t pk = pk4fp8(v[0], v[1], v[2], v[3]);
    dst[lane * 4 + (j >> 1)]     = (ushort_t)(pk & 0xFFFFu);
    dst[lane * 4 + (j >> 1) + 1] = (ushort_t)(pk >> 16);
  }
}

__global__ void prep_planes(const void* __restrict__ fxy,
                            const void* __restrict__ fxz,
                            const void* __restrict__ fyz,
                            ushort_t* __restrict__ ws) {
  const int isbf = (int)((const uint_t*)ws)[0];
  int t = blockIdx.x * 256 + threadIdx.x;   // 3*16384 = 49152
  int plane = t >> 14, pos = t & 16383;
  const void* src = (plane == 0) ? fxy : (plane == 1) ? fxz : fyz;
  ushort_t* d = ws + OFF_PL + (size_t)plane * 131072 + (size_t)pos * 8;
  for (int r = 0; r < 8; ++r) d[r] = ldbf(src, (long)r * 16384 + pos, isbf);
}

// ------------------------------------------------------------------
// main: R15 structure + MX K=64 MFMA (2x rate, m59: 4686 TF).
// block = 256 thr / 4 waves / 128 pts, 2 waves/SIMD.
// Wave w: out-cols [w*64, w*64+64) x all 128 pts; acc[2][4] f32x16 =
// 128 AGPRs. Per group g (4 kt = one K=64 step): 8 MX-MFMAs (2 mi x 4 d).
// A double-buffered one group ahead (a[2][2] = 32 regs); B ping-pong
// one d ahead (b[2] = 16 regs) -> ~252/256 regs, no spill expected.
// CUR tracks which A-buffer holds this layer's group 0 (flips when G odd).
// Peeled: last group prefetches NEXT layer's group 0 (no cold start).
// ------------------------------------------------------------------
template <int KT, int CUR>
__device__ __forceinline__ void mlp_layer(uchar_t* s_act,
                                          const uchar_t* __restrict__ wsW,
                                          const uchar_t* __restrict__ nextW,
                                          const ushort_t* __restrict__ bias,
                                          int w, int lane, AU (&a)[2][2]) {
  constexpr int G = KT / 4;
  f32x16 acc[2][4] = {};
  const int p31 = lane & 31;
  const int q2 = lane >> 5;
  const uchar_t* bptr = s_act + lane * 8;               // + d*8192 + kt*512
  const uchar_t* aptr = wsW + w * 1024 + lane * 8;      // + kt*4096 + mi*512
  const uchar_t* nptr = nextW + w * 1024 + lane * 8;
  AU b[2];
#pragma unroll
  for (int g = 0; g < G; ++g) {
    const int c = (CUR + g) & 1;
    // prefetch next group's A (or next layer's group 0) into the other buffer
    const uchar_t* ap = (g + 1 < G) ? (aptr + (size_t)(g + 1) * 16384) : nptr;
#pragma unroll
    for (int mi = 0; mi < 2; ++mi)
#pragma unroll
      for (int s = 0; s < 4; ++s)
        a[c ^ 1][mi].u2[s] = *(const uint2*)(ap + s * 4096 + mi * 512);
    const uchar_t* bg = bptr + g * 2048;
#pragma unroll
    for (int s = 0; s < 4; ++s) b[0].u2[s] = *(const uint2*)(bg + s * 512);
#pragma unroll
    for (int d = 0; d < 4; ++d) {
      if (d < 3) {
#pragma unroll
        for (int s = 0; s < 4; ++s)
          b[(d + 1) & 1].u2[s] = *(const uint2*)(bg + (d + 1) * 8192 + s * 512);
      }
      acc[0][d] = mx_mfma(a[c][0], b[d & 1], acc[0][d]);
      acc[1][d] = mx_mfma(a[c][1], b[d & 1], acc[1][d]);
    }
  }
  __syncthreads();   // all waves done reading act
  // Epilogue: z = acc/16 + bias (fmaf), relu, HW fp8-pack 4 cols -> b32 write.
  uchar_t* wbase = s_act + w * 2048 + p31 * 8 + q2 * 4;
#pragma unroll
  for (int mi = 0; mi < 2; ++mi) {
#pragma unroll
    for (int rq = 0; rq < 4; ++rq) {
      int col0 = w * 64 + mi * 32 + rq * 8 + q2 * 4;
      ushort4 bb = *(const ushort4*)(bias + col0);
      float bf0 = bf2f(bb.x), bf1 = bf2f(bb.y), bf2v = bf2f(bb.z), bf3 = bf2f(bb.w);
#pragma unroll
      for (int d = 0; d < 4; ++d) {
        const f32x16& A = acc[mi][d];
        float v0 = fmaxf(fmaf(A[rq * 4 + 0], 0.0625f, bf0), 0.0f);
        float v1 = fmaxf(fmaf(A[rq * 4 + 1], 0.0625f, bf1), 0.0f);
        float v2 = fmaxf(fmaf(A[rq * 4 + 2], 0.0625f, bf2v), 0.0f);
        float v3 = fmaxf(fmaf(A[rq * 4 + 3], 0.0625f, bf3), 0.0f);
        *(uint_t*)(wbase + d * 8192 + mi * 1024 + (rq >> 1) * 512 + (rq & 1) * 256)
            = pk4fp8(v0, v1, v2, v3);
      }
    }
  }
  __syncthreads();   // act ready for next layer
}

__global__ __launch_bounds__(256, 2)
void tensorf_main(const void* __restrict__ x,
                  const ushort_t* __restrict__ ws,
                  void* __restrict__ out) {
  __shared__ uchar_t s_act[4 * 16 * 512];   // 32 KB fp8 frag-native act
  const int isbf = (int)((const uint_t*)ws)[0];
  const int tid = threadIdx.x;
  const int lane = tid & 63;
  const int wid = tid >> 6;        // 0..3
  const int blk = blockIdx.x;

  // Layer-0 A-prefetch (group 0 = tiles 0..3) first: hides under Phase A.
  AU a[2][2];
  {
    const uchar_t* a0 = (const uchar_t*)(ws + OFF_W0) + wid * 1024 + lane * 8;
#pragma unroll
    for (int mi = 0; mi < 2; ++mi)
#pragma unroll
      for (int s = 0; s < 4; ++s)
        a[0][mi].u2[s] = *(const uint2*)(a0 + s * 4096 + mi * 512);
  }

  // ---- Phase A: features + PE into fp8 frag layout, cols 0..63 ----
  // 2 threads per point: s=0 gather + x + lvl 4,5 + pad; s=1 lvl 0..3
  {
    int pl = tid >> 1;            // 0..127
    int s = tid & 1;
    long p = (long)blk * 128 + pl;
    float x0 = ldf(x, p * 3 + 0, isbf);
    float x1 = ldf(x, p * 3 + 1, isbf);
    float x2 = ldf(x, p * 3 + 2, isbf);
    float fx[3] = { x0, x1, x2 };
    if (s == 0) {
      int ix = (int)(((x0 + 1.0f) * 0.5f) * 127.0f);
      int iy = (int)(((x1 + 1.0f) * 0.5f) * 127.0f);
      int iz = (int)(((x2 + 1.0f) * 0.5f) * 127.0f);
      ix = ix < 0 ? 0 : (ix > 127 ? 127 : ix);
      iy = iy < 0 ? 0 : (iy > 127 ? 127 : iy);
      iz = iz < 0 ? 0 : (iz > 127 ? 127 : iz);
      union { uint4 u; ushort_t s[8]; } a4, b4, c4;
      a4.u = *(const uint4*)(ws + OFF_PL + (size_t)(iy * 128 + ix) * 8);
      b4.u = *(const uint4*)(ws + OFF_PL + 131072 + (size_t)(iz * 128 + ix) * 8);
      c4.u = *(const uint4*)(ws + OFF_PL + 262144 + (size_t)(iz * 128 + iy) * 8);
      float fv[8];
#pragma unroll
      for (int r = 0; r < 8; ++r)
        fv[r] = bf2f(a4.s[r]) + bf2f(b4.s[r]) + bf2f(c4.s[r]);
      uint2 f;
      f.x = pk4fp8(fv[0], fv[1], fv[2], fv[3]);
      f.y = pk4fp8(fv[4], fv[5], fv[6], fv[7]);
      *(uint2*)(s_act + fp8addr(pl, 0)) = f;         // cols 0..7, 8B aligned
      s_act[fp8addr(pl, 8)]  = f2fp8(x0);
      s_act[fp8addr(pl, 9)]  = f2fp8(x1);
      s_act[fp8addr(pl, 10)] = f2fp8(x2);
#pragma unroll
      for (int l = 4; l < 6; ++l) {
        float fr = (float)(1 << l);
        int k0 = 11 + l * 6;
#pragma unroll
        for (int dd = 0; dd < 3; ++dd) {
          float ang = fx[dd] * fr;
          s_act[fp8addr(pl, k0 + dd)]     = f2fp8(__sinf(ang));
          s_act[fp8addr(pl, k0 + 3 + dd)] = f2fp8(__cosf(ang));
        }
      }
      s_act[fp8addr(pl, 47)] = 0;
      *(uint2*)(s_act + fp8addr(pl, 48)) = uint2{0u, 0u};
      *(uint2*)(s_act + fp8addr(pl, 56)) = uint2{0u, 0u};
    } else {
#pragma unroll
      for (int l = 0; l < 4; ++l) {
        float fr = (float)(1 << l);
        int k0 = 11 + l * 6;
#pragma unroll
        for (int dd = 0; dd < 3; ++dd) {
          float ang = fx[dd] * fr;
          s_act[fp8addr(pl, k0 + dd)]     = f2fp8(__sinf(ang));
          s_act[fp8addr(pl, k0 + 3 + dd)] = f2fp8(__cosf(ang));
        }
      }
    }
  }
  __syncthreads();

  const uchar_t* w0 = (const uchar_t*)(ws + OFF_W0);
  const uchar_t* w1 = (const uchar_t*)(ws + OFF_W1);
  const uchar_t* w2 = (const uchar_t*)(ws + OFF_W2);
  const uchar_t* w3 = (const uchar_t*)(ws + OFF_W3);
  const uchar_t* wh = (const uchar_t*)(ws + OFF_WH);
  // CUR tracking: layer0 G=1 flips 0->1; layers 1-3 G=4 keep CUR=1.
  mlp_layer<4, 0>(s_act,  w0, w1, ws + OFF_B0, wid, lane, a);
  mlp_layer<16, 1>(s_act, w1, w2, ws + OFF_B1, wid, lane, a);
  mlp_layer<16, 1>(s_act, w2, w3, ws + OFF_B2, wid, lane, a);
  mlp_layer<16, 1>(s_act, w3, wh, ws + OFF_B3, wid, lane, a);

  // ---- head: D = Wh^T(32x256, cols 0..3 real) x Act^T; wave w = n-tile w ----
  {
    f32x16 acc = {};
    const int p31 = lane & 31;
    const int q2 = lane >> 5;
    const uchar_t* hb = s_act + wid * 8192 + lane * 8;
    const uchar_t* whp = wh + lane * 8;
    AU ta, tb;
#pragma unroll
    for (int g = 0; g < 4; ++g) {
#pragma unroll
      for (int s = 0; s < 4; ++s) {
        ta.u2[s] = *(const uint2*)(whp + (size_t)(4 * g + s) * 512);
        tb.u2[s] = *(const uint2*)(hb + (size_t)(4 * g + s) * 512);
      }
      acc = mx_mfma(ta, tb, acc);
    }
    if (q2 == 0) {   // regs 0..3 = cols 0..3 = rgb0, rgb1, rgb2, sigma
      long pp = (long)blk * 128 + wid * 32 + p31;
      float br0 = bf2f(ws[OFF_BRGB + 0]), br1 = bf2f(ws[OFF_BRGB + 1]), br2 = bf2f(ws[OFF_BRGB + 2]);
      float bs = bf2f(ws[OFF_BSIG]);
      float z0 = fmaf(acc[0], 0.0625f, br0);
      float z1 = fmaf(acc[1], 0.0625f, br1);
      float z2 = fmaf(acc[2], 0.0625f, br2);
      stf(out, pp * 3 + 0, isbf, 1.0f / (1.0f + __expf(-z0)));
      stf(out, pp * 3 + 1, isbf, 1.0f / (1.0f + __expf(-z1)));
      stf(out, pp * 3 + 2, isbf, 1.0f / (1.0f + __expf(-z2)));
      float zs = fmaf(acc[3], 0.0625f, bs);
      float sp = (zs > 20.0f) ? zs : __logf(1.0f + __expf(zs));
      stf(out, (long)3 * NPTS + pp, isbf, sp);
    }
  }
}

extern "C" void kernel_launch(void* const* d_in, const int* in_sizes, int n_in,
                              void* d_out, int out_size, void* d_ws, size_t ws_size,
                              hipStream_t stream) {
  const void* x    = d_in[0];
  const void* fxy  = d_in[1];
  const void* fxz  = d_in[2];
  const void* fyz  = d_in[3];
  const void* W0   = d_in[4];
  const void* b0   = d_in[5];
  const void* W1   = d_in[6];
  const void* b1   = d_in[7];
  const void* W2   = d_in[8];
  const void* b2   = d_in[9];
  const void* W3   = d_in[10];
  const void* b3   = d_in[11];
  const void* Wsig = d_in[12];
  const void* bsig = d_in[13];
  const void* Wrgb = d_in[14];
  const void* brgb = d_in[15];
  ushort_t* ws = (ushort_t*)d_ws;

  hipLaunchKernelGGL(sniff_dtype, dim3(1), dim3(64), 0, stream, fxy, ws);
  hipLaunchKernelGGL(prep_bias, dim3(1), dim3(256), 0, stream,
                     b0, b1, b2, b3, bsig, brgb, ws);
  hipLaunchKernelGGL(prep_weights, dim3(108), dim3(256), 0, stream,
                     W0, W1, W2, W3, Wsig, Wrgb, ws);
  hipLaunchKernelGGL(prep_planes, dim3(192), dim3(256), 0, stream,
                     fxy, fxz, fyz, ws);
  hipLaunchKernelGGL(tensorf_main, dim3(8192), dim3(256), 0, stream,
                     x, ws, d_out);
}